// Round 3
// baseline (377.289 us; speedup 1.0000x reference)
//
#include <hip/hip_runtime.h>
#include <hip/hip_bf16.h>
#include <stdint.h>

#define OUT_N 4096
#define IN_N  4096
#define BATCH 2048
#define KHALF 2049   // IN/2 + 1

typedef __bf16 bf16x8 __attribute__((ext_vector_type(8)));
typedef float  f32x4  __attribute__((ext_vector_type(4)));

__device__ __forceinline__ unsigned short f2bf(float f) {
  unsigned int u = __builtin_bit_cast(unsigned int, f);
  u += 0x7FFFu + ((u >> 16) & 1u);   // round-to-nearest-even
  return (unsigned short)(u >> 16);
}

// ---------------------------------------------------------------------------
// complex helpers
// ---------------------------------------------------------------------------
__device__ __forceinline__ float2 cmul(float2 a, float2 b) {
  return make_float2(a.x * b.x - a.y * b.y, a.x * b.y + a.y * b.x);
}
__device__ __forceinline__ float2 cadd(float2 a, float2 b) { return make_float2(a.x + b.x, a.y + b.y); }
__device__ __forceinline__ float2 csub(float2 a, float2 b) { return make_float2(a.x - b.x, a.y - b.y); }
__device__ __forceinline__ float2 muli(float2 a) { return make_float2(-a.y, a.x); }  // *e^{+i pi/2}

// inverse DFT4 (w = +i)
__device__ __forceinline__ void dft4i(float2& x0, float2& x1, float2& x2, float2& x3) {
  float2 t0 = cadd(x0, x2), t1 = csub(x0, x2);
  float2 t2 = cadd(x1, x3), t3 = csub(x1, x3);
  float2 it3 = muli(t3);
  x0 = cadd(t0, t2); x2 = csub(t0, t2);
  x1 = cadd(t1, it3); x3 = csub(t1, it3);
}

#define C8f  0.70710678118654752f
#define C16f 0.92387953251128676f
#define S16f 0.38268343236508977f

// inverse DFT16 in registers
__device__ __forceinline__ void dft16i(float2 r[16]) {
  float2 t[16];
#pragma unroll
  for (int b = 0; b < 4; ++b) {
    float2 a0 = r[b], a1 = r[4 + b], a2 = r[8 + b], a3 = r[12 + b];
    dft4i(a0, a1, a2, a3);
    t[b * 4 + 0] = a0; t[b * 4 + 1] = a1; t[b * 4 + 2] = a2; t[b * 4 + 3] = a3;
  }
  const float2 W1 = make_float2(C16f, S16f);
  const float2 W2 = make_float2(C8f, C8f);
  const float2 W3 = make_float2(S16f, C16f);
  const float2 W6 = make_float2(-C8f, C8f);
  const float2 W9 = make_float2(-C16f, -S16f);
  t[5]  = cmul(t[5],  W1);  t[6]  = cmul(t[6],  W2);  t[7]  = cmul(t[7],  W3);
  t[9]  = cmul(t[9],  W2);  t[10] = muli(t[10]);      t[11] = cmul(t[11], W6);
  t[13] = cmul(t[13], W3);  t[14] = cmul(t[14], W6);  t[15] = cmul(t[15], W9);
#pragma unroll
  for (int q = 0; q < 4; ++q) {
    float2 a0 = t[q], a1 = t[4 + q], a2 = t[8 + q], a3 = t[12 + q];
    dft4i(a0, a1, a2, a3);
    r[q] = a0; r[q + 4] = a1; r[q + 8] = a2; r[q + 12] = a3;
  }
}

// apply r[k] *= e^{i k theta} for k=1..15 via recurrence
__device__ __forceinline__ void twiddle16(float2 r[16], float theta) {
  float sn, cs;
  __sincosf(theta, &sn, &cs);
  float2 w = make_float2(cs, sn);
  float2 wk = w;
  r[1] = cmul(r[1], wk);
#pragma unroll
  for (int k = 2; k < 16; ++k) {
    wk = cmul(wk, w);
    r[k] = cmul(r[k], wk);
  }
}

// ---------------------------------------------------------------------------
// 4096-pt inverse FFT (unnormalized, e^{+i}), radix 16^3 in registers.
// Entry: thread t holds r[n1] = x[256*n1 + t].  Exit: r[d] = X[t + 256*d].
// lds >= 4368 float2. Caller must sync before calling if lds fed r.
// ---------------------------------------------------------------------------
__device__ void fft4096_core(float2 r[16], float2* lds, int t) {
  dft16i(r);
  twiddle16(r, 1.53398078788564123e-3f * (float)t);   // 2*pi/4096 * t
#pragma unroll
  for (int k1 = 0; k1 < 16; ++k1) lds[k1 * 257 + t] = r[k1];
  __syncthreads();
  const int k1 = t & 15, b = t >> 4;
  float2 s[16];
#pragma unroll
  for (int a = 0; a < 16; ++a) s[a] = lds[k1 * 257 + 16 * a + b];
  __syncthreads();
  dft16i(s);
  twiddle16(s, 2.45436926061702596e-2f * (float)b);   // 2*pi/256 * b
#pragma unroll
  for (int c = 0; c < 16; ++c) lds[k1 * 273 + c * 17 + b] = s[c];
  __syncthreads();
#pragma unroll
  for (int bb = 0; bb < 16; ++bb) r[bb] = lds[k1 * 273 + b * 17 + bb];
  dft16i(r);
}

// ---------------------------------------------------------------------------
// P1: mask + transpose. W[o][k] (k<2049) -> WT[k][o] (complex float2)
// ---------------------------------------------------------------------------
__global__ void mask_transpose(const float* __restrict__ wr, const float* __restrict__ wi,
                               const int* __restrict__ zmat, float2* __restrict__ wt) {
  __shared__ float2 tile[32][33];
  const int k0 = blockIdx.x * 32;
  const int o0 = blockIdx.y * 32;
  const int tx = threadIdx.x;   // 0..31
  const int ty = threadIdx.y;   // 0..7
#pragma unroll
  for (int r = 0; r < 4; ++r) {
    int o = o0 + ty + r * 8;
    int k = k0 + tx;
    float2 v = make_float2(0.f, 0.f);
    if (k < KHALF) {
      size_t idx = (size_t)o * IN_N + k;
      if (zmat[idx] <= 8388608) v = make_float2(wr[idx], wi[idx]);
    }
    tile[ty + r * 8][tx] = v;
  }
  __syncthreads();
#pragma unroll
  for (int r = 0; r < 4; ++r) {
    int k = k0 + ty + r * 8;
    int o = o0 + tx;
    if (k < KHALF) wt[(size_t)k * OUT_N + o] = tile[tx][ty + r * 8];
  }
}

// ---------------------------------------------------------------------------
// P2: per-row inverse FFT of WT, in place, UNnormalized (1/4096^2 in P4)
// ---------------------------------------------------------------------------
__global__ __launch_bounds__(256) void col_ifft(float2* __restrict__ wt) {
  __shared__ float2 lds[4368];
  const int t = threadIdx.x;
  float2* row = wt + (size_t)blockIdx.x * OUT_N;
  float2 r[16];
#pragma unroll
  for (int n1 = 0; n1 < 16; ++n1) r[n1] = row[n1 * 256 + t];
  fft4096_core(r, lds, t);
#pragma unroll
  for (int d = 0; d < 16; ++d) row[t + 256 * d] = r[d];
}

// ---------------------------------------------------------------------------
// P3: transpose YT[k][o] (2049 x 4096) -> Y[o][k] (4096 x 2049)
// ---------------------------------------------------------------------------
__global__ void transpose_ko(const float2* __restrict__ yt, float2* __restrict__ y) {
  __shared__ float2 tile[32][33];
  const int k0 = blockIdx.x * 32;
  const int o0 = blockIdx.y * 32;
  const int tx = threadIdx.x;
  const int ty = threadIdx.y;
#pragma unroll
  for (int r = 0; r < 4; ++r) {
    int k = k0 + ty + r * 8;
    int o = o0 + tx;
    if (k < KHALF) tile[ty + r * 8][tx] = yt[(size_t)k * OUT_N + o];
  }
  __syncthreads();
#pragma unroll
  for (int r = 0; r < 4; ++r) {
    int o = o0 + ty + r * 8;
    int k = k0 + tx;
    if (k < KHALF) y[(size_t)o * KHALF + k] = tile[tx][ty + r * 8];
  }
}

// ---------------------------------------------------------------------------
// P4: TWO rows per block. irfft(Ya) and irfft(Yb) are real, so
// ifft(Ya_ext + i*Yb_ext) = a + i*b exactly — one 4096-pt FFT for 2 rows.
// Scale = 1/(4096*4096) (covers P2's skipped normalization too).
// ---------------------------------------------------------------------------
__global__ __launch_bounds__(256) void row_irfft2(const float2* __restrict__ y,
                                                  unsigned short* __restrict__ wbf) {
  __shared__ float2 lds[4368];
  const int t = threadIdx.x;
  const int oa = blockIdx.x * 2, ob = oa + 1;
  const float2* rowa = y + (size_t)oa * KHALF;
  const float2* rowb = y + (size_t)ob * KHALF;
  float2* lsa = lds;          // [0, 2049)
  float2* lsb = lds + 2049;   // [2049, 4098)
#pragma unroll
  for (int j = 0; j < 9; ++j) {
    int k = t + j * 256;
    if (k < KHALF) { lsa[k] = rowa[k]; lsb[k] = rowb[k]; }
  }
  __syncthreads();
  float2 r[16];
#pragma unroll
  for (int n1 = 0; n1 < 16; ++n1) {
    int m = n1 * 256 + t;
    float2 za, zb;
    if (m == 0)        { za = make_float2(lsa[0].x, 0.f);    zb = make_float2(lsb[0].x, 0.f); }
    else if (m < 2048) { za = lsa[m];                        zb = lsb[m]; }
    else if (m == 2048){ za = make_float2(lsa[2048].x, 0.f); zb = make_float2(lsb[2048].x, 0.f); }
    else { float2 ua = lsa[4096 - m], ub = lsb[4096 - m];
           za = make_float2(ua.x, -ua.y); zb = make_float2(ub.x, -ub.y); }
    r[n1] = make_float2(za.x - zb.y, za.y + zb.x);   // za + i*zb
  }
  __syncthreads();
  fft4096_core(r, lds, t);
  const float sc = 1.0f / (4096.0f * 4096.0f);
  unsigned short* orow_a = wbf + (size_t)oa * IN_N;
  unsigned short* orow_b = wbf + (size_t)ob * IN_N;
#pragma unroll
  for (int d = 0; d < 16; ++d) {
    orow_a[t + 256 * d] = f2bf(r[d].x * sc);
    orow_b[t + 256 * d] = f2bf(r[d].y * sc);
  }
}

// ---------------------------------------------------------------------------
// P5: data f32 -> bf16
// ---------------------------------------------------------------------------
__global__ void cvt_bf16(const float* __restrict__ x, unsigned short* __restrict__ o, int n4) {
  int i = blockIdx.x * blockDim.x + threadIdx.x;
  if (i < n4) {
    float4 v = ((const float4*)x)[i];
    ushort4 r;
    r.x = f2bf(v.x); r.y = f2bf(v.y); r.z = f2bf(v.z); r.w = f2bf(v.w);
    ((ushort4*)o)[i] = r;
  }
}

// ---------------------------------------------------------------------------
// P6: C[M,N] = A[M,K] * B[N,K]^T + bias  (bf16 in, f32 out)
// 512 threads / 8 waves per block, 128x128 tile: 16 waves/CU (vs 8 with
// 256-thr blocks at this grid) to hide the staging-drain barrier stall.
// Waves arranged 2(M) x 4(N); each wave computes 64x32 via 4x2 MFMAs.
// ---------------------------------------------------------------------------
__device__ __forceinline__ void gload_lds16(const void* gp, void* lp) {
  typedef const __attribute__((address_space(1))) void* gptr_t;
  typedef __attribute__((address_space(3))) void* lptr_t;
  __builtin_amdgcn_global_load_lds((gptr_t)(unsigned long long)gp,
                                   (lptr_t)(unsigned int)(unsigned long long)lp,
                                   16, 0, 0);
}

__global__ __launch_bounds__(512) void gemm_bt_bias(const unsigned short* __restrict__ A,
                                                    const unsigned short* __restrict__ B,
                                                    const float* __restrict__ bias,
                                                    float* __restrict__ C) {
  __shared__ __align__(16) unsigned short As[128 * 32];
  __shared__ __align__(16) unsigned short Bs[128 * 32];
  const int tid  = threadIdx.x;
  const int wave = tid >> 6;      // 0..7
  const int lane = tid & 63;
  const int gm0 = blockIdx.y * 128;
  const int gn0 = blockIdx.x * 128;

  f32x4 acc[4][2] = {};
  const int wm = wave >> 2, wn = wave & 3;   // 2x4 waves, 64x32 each
  const int lrow = lane >> 2;                // 0..15
  const int lcol = (lane & 3) * 8;           // 0,8,16,24
  const int rbase = wave * 16;               // this wave stages rows [rbase, rbase+16)

  for (int kt = 0; kt < IN_N; kt += 32) {
    gload_lds16(A + ((size_t)(gm0 + rbase + lrow) * IN_N + kt + lcol),
                As + (size_t)rbase * 32);
    gload_lds16(B + ((size_t)(gn0 + rbase + lrow) * IN_N + kt + lcol),
                Bs + (size_t)rbase * 32);
    __syncthreads();   // drains vmcnt (global_load_lds)

    bf16x8 af[4], bfr[2];
#pragma unroll
    for (int i = 0; i < 4; ++i)
      af[i]  = *(const bf16x8*)&As[(wm * 64 + i * 16 + (lane & 15)) * 32 + (lane >> 4) * 8];
#pragma unroll
    for (int j = 0; j < 2; ++j)
      bfr[j] = *(const bf16x8*)&Bs[(wn * 32 + j * 16 + (lane & 15)) * 32 + (lane >> 4) * 8];
#pragma unroll
    for (int mi = 0; mi < 4; ++mi)
#pragma unroll
      for (int ni = 0; ni < 2; ++ni)
        acc[mi][ni] = __builtin_amdgcn_mfma_f32_16x16x32_bf16(af[mi], bfr[ni], acc[mi][ni], 0, 0, 0);
    __syncthreads();
  }

  // epilogue: C/D layout col = lane&15, row = (lane>>4)*4 + r   [m89/m91]
  const int col0 = gn0 + wn * 32 + (lane & 15);
  const int row0 = gm0 + wm * 64 + (lane >> 4) * 4;
#pragma unroll
  for (int mi = 0; mi < 4; ++mi) {
#pragma unroll
    for (int ni = 0; ni < 2; ++ni) {
      int col = col0 + ni * 16;
      float bv = bias[col];
#pragma unroll
      for (int r = 0; r < 4; ++r) {
        int row = row0 + mi * 16 + r;
        C[(size_t)row * OUT_N + col] = acc[mi][ni][r] + bv;
      }
    }
  }
}

// ---------------------------------------------------------------------------
extern "C" void kernel_launch(void* const* d_in, const int* in_sizes, int n_in,
                              void* d_out, int out_size, void* d_ws, size_t ws_size,
                              hipStream_t stream) {
  const float* data = (const float*)d_in[0];
  const float* wr   = (const float*)d_in[1];
  const float* wi   = (const float*)d_in[2];
  const float* bias = (const float*)d_in[3];
  const int*   zmat = (const int*)d_in[4];

  char* ws = (char*)d_ws;
  // region 0: [0, 67,141,632)  WT (then reused for wbf+dbf)
  // region 1: [67,141,632, 134,283,264)  Y
  float2* wt = (float2*)ws;                                  // 2049*4096*8
  float2* y  = (float2*)(ws + 67141632ull);                  // 4096*2049*8
  unsigned short* wbf = (unsigned short*)ws;                 // 4096*4096*2 = 33,554,432
  unsigned short* dbf = (unsigned short*)(ws + 33554432ull); // 2048*4096*2 = 16,777,216

  hipLaunchKernelGGL(mask_transpose, dim3(65, 128), dim3(32, 8), 0, stream, wr, wi, zmat, wt);
  hipLaunchKernelGGL(col_ifft,       dim3(2049),    dim3(256),   0, stream, wt);
  hipLaunchKernelGGL(transpose_ko,   dim3(65, 128), dim3(32, 8), 0, stream, wt, y);
  hipLaunchKernelGGL(row_irfft2,     dim3(2048),    dim3(256),   0, stream, y, wbf);
  hipLaunchKernelGGL(cvt_bf16,       dim3(8192),    dim3(256),   0, stream, data, dbf, (BATCH * IN_N) / 4);
  hipLaunchKernelGGL(gemm_bt_bias,   dim3(OUT_N / 128, BATCH / 128), dim3(512), 0, stream,
                     dbf, wbf, bias, (float*)d_out);
}

// Round 4
// 362.578 us; speedup vs baseline: 1.0406x; 1.0406x over previous
//
#include <hip/hip_runtime.h>
#include <hip/hip_bf16.h>
#include <stdint.h>

#define OUT_N 4096
#define IN_N  4096
#define BATCH 2048
#define KHALF 2049   // IN/2 + 1

typedef __bf16 bf16x8 __attribute__((ext_vector_type(8)));
typedef float  f32x4  __attribute__((ext_vector_type(4)));

__device__ __forceinline__ unsigned short f2bf(float f) {
  unsigned int u = __builtin_bit_cast(unsigned int, f);
  u += 0x7FFFu + ((u >> 16) & 1u);   // round-to-nearest-even
  return (unsigned short)(u >> 16);
}

// ---------------------------------------------------------------------------
// complex helpers
// ---------------------------------------------------------------------------
__device__ __forceinline__ float2 cmul(float2 a, float2 b) {
  return make_float2(a.x * b.x - a.y * b.y, a.x * b.y + a.y * b.x);
}
__device__ __forceinline__ float2 cadd(float2 a, float2 b) { return make_float2(a.x + b.x, a.y + b.y); }
__device__ __forceinline__ float2 csub(float2 a, float2 b) { return make_float2(a.x - b.x, a.y - b.y); }
__device__ __forceinline__ float2 muli(float2 a) { return make_float2(-a.y, a.x); }  // *e^{+i pi/2}

// inverse DFT4 (w = +i)
__device__ __forceinline__ void dft4i(float2& x0, float2& x1, float2& x2, float2& x3) {
  float2 t0 = cadd(x0, x2), t1 = csub(x0, x2);
  float2 t2 = cadd(x1, x3), t3 = csub(x1, x3);
  float2 it3 = muli(t3);
  x0 = cadd(t0, t2); x2 = csub(t0, t2);
  x1 = cadd(t1, it3); x3 = csub(t1, it3);
}

#define C8f  0.70710678118654752f
#define C16f 0.92387953251128676f
#define S16f 0.38268343236508977f

// inverse DFT16 in registers
__device__ __forceinline__ void dft16i(float2 r[16]) {
  float2 t[16];
#pragma unroll
  for (int b = 0; b < 4; ++b) {
    float2 a0 = r[b], a1 = r[4 + b], a2 = r[8 + b], a3 = r[12 + b];
    dft4i(a0, a1, a2, a3);
    t[b * 4 + 0] = a0; t[b * 4 + 1] = a1; t[b * 4 + 2] = a2; t[b * 4 + 3] = a3;
  }
  const float2 W1 = make_float2(C16f, S16f);
  const float2 W2 = make_float2(C8f, C8f);
  const float2 W3 = make_float2(S16f, C16f);
  const float2 W6 = make_float2(-C8f, C8f);
  const float2 W9 = make_float2(-C16f, -S16f);
  t[5]  = cmul(t[5],  W1);  t[6]  = cmul(t[6],  W2);  t[7]  = cmul(t[7],  W3);
  t[9]  = cmul(t[9],  W2);  t[10] = muli(t[10]);      t[11] = cmul(t[11], W6);
  t[13] = cmul(t[13], W3);  t[14] = cmul(t[14], W6);  t[15] = cmul(t[15], W9);
#pragma unroll
  for (int q = 0; q < 4; ++q) {
    float2 a0 = t[q], a1 = t[4 + q], a2 = t[8 + q], a3 = t[12 + q];
    dft4i(a0, a1, a2, a3);
    r[q] = a0; r[q + 4] = a1; r[q + 8] = a2; r[q + 12] = a3;
  }
}

// apply r[k] *= e^{i k theta} for k=1..15 via recurrence
__device__ __forceinline__ void twiddle16(float2 r[16], float theta) {
  float sn, cs;
  __sincosf(theta, &sn, &cs);
  float2 w = make_float2(cs, sn);
  float2 wk = w;
  r[1] = cmul(r[1], wk);
#pragma unroll
  for (int k = 2; k < 16; ++k) {
    wk = cmul(wk, w);
    r[k] = cmul(r[k], wk);
  }
}

// ---------------------------------------------------------------------------
// 4096-pt inverse FFT (unnormalized, e^{+i}), radix 16^3 in registers.
// Entry: thread t holds r[n1] = x[256*n1 + t].  Exit: r[d] = X[t + 256*d].
// lds >= 4368 float2. Caller must sync before calling if lds fed r.
// ---------------------------------------------------------------------------
__device__ void fft4096_core(float2 r[16], float2* lds, int t) {
  dft16i(r);
  twiddle16(r, 1.53398078788564123e-3f * (float)t);   // 2*pi/4096 * t
#pragma unroll
  for (int k1 = 0; k1 < 16; ++k1) lds[k1 * 257 + t] = r[k1];
  __syncthreads();
  const int k1 = t & 15, b = t >> 4;
  float2 s[16];
#pragma unroll
  for (int a = 0; a < 16; ++a) s[a] = lds[k1 * 257 + 16 * a + b];
  __syncthreads();
  dft16i(s);
  twiddle16(s, 2.45436926061702596e-2f * (float)b);   // 2*pi/256 * b
#pragma unroll
  for (int c = 0; c < 16; ++c) lds[k1 * 273 + c * 17 + b] = s[c];
  __syncthreads();
#pragma unroll
  for (int bb = 0; bb < 16; ++bb) r[bb] = lds[k1 * 273 + b * 17 + bb];
  dft16i(r);
}

// ---------------------------------------------------------------------------
// P1: mask + transpose. W[o][k] (k<2049) -> WT[k][o] (complex float2)
// 64(k) x 32(o) tiles, float2/int2 loads. blockIdx.x==32 handles k=2048.
// ---------------------------------------------------------------------------
__global__ void mask_transpose(const float* __restrict__ wr, const float* __restrict__ wi,
                               const int* __restrict__ zmat, float2* __restrict__ wt) {
  __shared__ float2 tile[32][65];   // [o-local][k-local], pitch 65 -> 2-way (free)
  const int tx = threadIdx.x;       // 0..31
  const int ty = threadIdx.y;       // 0..7
  const int o0 = blockIdx.y * 32;
  if (blockIdx.x == 32) {           // Nyquist column k = 2048
    int t = ty * 32 + tx;
    if (t < 32) {
      int o = o0 + t;
      size_t idx = (size_t)o * IN_N + 2048;
      float2 v = make_float2(0.f, 0.f);
      if (zmat[idx] <= 8388608) v = make_float2(wr[idx], wi[idx]);
      wt[(size_t)2048 * OUT_N + o] = v;
    }
    return;
  }
  const int k0 = blockIdx.x * 64;
#pragma unroll
  for (int r = 0; r < 4; ++r) {
    int o = o0 + ty + r * 8;
    size_t base = (size_t)o * IN_N + k0 + tx * 2;
    float2 vr = *(const float2*)&wr[base];
    float2 vi = *(const float2*)&wi[base];
    int2   z  = *(const int2*)&zmat[base];
    tile[ty + r * 8][tx * 2]     = (z.x <= 8388608) ? make_float2(vr.x, vi.x) : make_float2(0.f, 0.f);
    tile[ty + r * 8][tx * 2 + 1] = (z.y <= 8388608) ? make_float2(vr.y, vi.y) : make_float2(0.f, 0.f);
  }
  __syncthreads();
#pragma unroll
  for (int rr = 0; rr < 8; ++rr) {
    int k = k0 + ty + rr * 8;
    int o = o0 + tx;
    wt[(size_t)k * OUT_N + o] = tile[tx][ty + rr * 8];
  }
}

// ---------------------------------------------------------------------------
// P2: per-row inverse FFT of WT, in place, UNnormalized (1/4096^2 in P4)
// ---------------------------------------------------------------------------
__global__ __launch_bounds__(256) void col_ifft(float2* __restrict__ wt) {
  __shared__ float2 lds[4368];
  const int t = threadIdx.x;
  float2* row = wt + (size_t)blockIdx.x * OUT_N;
  float2 r[16];
#pragma unroll
  for (int n1 = 0; n1 < 16; ++n1) r[n1] = row[n1 * 256 + t];
  fft4096_core(r, lds, t);
#pragma unroll
  for (int d = 0; d < 16; ++d) row[t + 256 * d] = r[d];
}

// ---------------------------------------------------------------------------
// P3: transpose YT[k][o] (2049 x 4096) -> Y[o][k] (4096 x 2049)
// ---------------------------------------------------------------------------
__global__ void transpose_ko(const float2* __restrict__ yt, float2* __restrict__ y) {
  __shared__ float2 tile[32][33];
  const int k0 = blockIdx.x * 32;
  const int o0 = blockIdx.y * 32;
  const int tx = threadIdx.x;
  const int ty = threadIdx.y;
#pragma unroll
  for (int r = 0; r < 4; ++r) {
    int k = k0 + ty + r * 8;
    int o = o0 + tx;
    if (k < KHALF) tile[ty + r * 8][tx] = yt[(size_t)k * OUT_N + o];
  }
  __syncthreads();
#pragma unroll
  for (int r = 0; r < 4; ++r) {
    int o = o0 + ty + r * 8;
    int k = k0 + tx;
    if (k < KHALF) y[(size_t)o * KHALF + k] = tile[tx][ty + r * 8];
  }
}

// ---------------------------------------------------------------------------
// P4: TWO rows per block: ifft(Ya_ext + i*Yb_ext) = a + i*b exactly.
// Scale = 1/(4096*4096) (covers P2's skipped normalization too).
// ---------------------------------------------------------------------------
__global__ __launch_bounds__(256) void row_irfft2(const float2* __restrict__ y,
                                                  unsigned short* __restrict__ wbf) {
  __shared__ float2 lds[4368];
  const int t = threadIdx.x;
  const int oa = blockIdx.x * 2, ob = oa + 1;
  const float2* rowa = y + (size_t)oa * KHALF;
  const float2* rowb = y + (size_t)ob * KHALF;
  float2* lsa = lds;          // [0, 2049)
  float2* lsb = lds + 2049;   // [2049, 4098)
#pragma unroll
  for (int j = 0; j < 9; ++j) {
    int k = t + j * 256;
    if (k < KHALF) { lsa[k] = rowa[k]; lsb[k] = rowb[k]; }
  }
  __syncthreads();
  float2 r[16];
#pragma unroll
  for (int n1 = 0; n1 < 16; ++n1) {
    int m = n1 * 256 + t;
    float2 za, zb;
    if (m == 0)        { za = make_float2(lsa[0].x, 0.f);    zb = make_float2(lsb[0].x, 0.f); }
    else if (m < 2048) { za = lsa[m];                        zb = lsb[m]; }
    else if (m == 2048){ za = make_float2(lsa[2048].x, 0.f); zb = make_float2(lsb[2048].x, 0.f); }
    else { float2 ua = lsa[4096 - m], ub = lsb[4096 - m];
           za = make_float2(ua.x, -ua.y); zb = make_float2(ub.x, -ub.y); }
    r[n1] = make_float2(za.x - zb.y, za.y + zb.x);   // za + i*zb
  }
  __syncthreads();
  fft4096_core(r, lds, t);
  const float sc = 1.0f / (4096.0f * 4096.0f);
  unsigned short* orow_a = wbf + (size_t)oa * IN_N;
  unsigned short* orow_b = wbf + (size_t)ob * IN_N;
#pragma unroll
  for (int d = 0; d < 16; ++d) {
    orow_a[t + 256 * d] = f2bf(r[d].x * sc);
    orow_b[t + 256 * d] = f2bf(r[d].y * sc);
  }
}

// ---------------------------------------------------------------------------
// P5: data f32 -> bf16
// ---------------------------------------------------------------------------
__global__ void cvt_bf16(const float* __restrict__ x, unsigned short* __restrict__ o, int n4) {
  int i = blockIdx.x * blockDim.x + threadIdx.x;
  if (i < n4) {
    float4 v = ((const float4*)x)[i];
    ushort4 r;
    r.x = f2bf(v.x); r.y = f2bf(v.y); r.z = f2bf(v.z); r.w = f2bf(v.w);
    ((ushort4*)o)[i] = r;
  }
}

// ---------------------------------------------------------------------------
// P6: C[M,N] = A[M,K] * B[N,K]^T + bias  (bf16 in, f32 out)
// 256 thr / 4 waves (2x2 of 64x64), 128x128 tile, BK=64, XOR-swizzled LDS.
// Swizzle: LDS[row][chunk c] holds global 16B-chunk (c ^ (row&7)); staging
// stays contiguous in lane order (global_load_lds requirement) while
// fragment ds_read_b128 spreads 16 rows over all 32 banks (2-way = free).
// ---------------------------------------------------------------------------
#define BK 64

__device__ __forceinline__ void gload_lds16(const void* gp, void* lp) {
  typedef const __attribute__((address_space(1))) void* gptr_t;
  typedef __attribute__((address_space(3))) void* lptr_t;
  __builtin_amdgcn_global_load_lds((gptr_t)(unsigned long long)gp,
                                   (lptr_t)(unsigned int)(unsigned long long)lp,
                                   16, 0, 0);
}

__global__ __launch_bounds__(256) void gemm_bt_bias(const unsigned short* __restrict__ A,
                                                    const unsigned short* __restrict__ B,
                                                    const float* __restrict__ bias,
                                                    float* __restrict__ C) {
  __shared__ __align__(16) unsigned short As[128 * BK];   // 16 KB
  __shared__ __align__(16) unsigned short Bs[128 * BK];   // 16 KB
  const int tid  = threadIdx.x;
  const int wave = tid >> 6;
  const int lane = tid & 63;
  const int gm0 = blockIdx.y * 128;
  const int gn0 = blockIdx.x * 128;

  f32x4 acc[4][4] = {};
  const int wm = wave >> 1, wn = wave & 1;     // 2x2 waves, 64x64 each
  // staging map: dest row r0+ (lane>>3), dest chunk lane&7 gets src chunk ^row
  const int srow   = lane >> 3;                // 0..7
  const int schunk = (lane & 7) ^ srow;        // XOR swizzle
  // fragment map
  const int l7 = lane & 7;
  const int qbase = lane >> 4;                 // 0..3
  const int fra = wm * 64 + (lane & 15);
  const int frb = wn * 64 + (lane & 15);

  for (int kt = 0; kt < IN_N; kt += BK) {
#pragma unroll
    for (int j = 0; j < 4; ++j) {
      const int r0 = wave * 32 + j * 8;        // 8-row chunk per load
      gload_lds16(A + ((size_t)(gm0 + r0 + srow) * IN_N + kt + schunk * 8),
                  As + (size_t)r0 * BK);
      gload_lds16(B + ((size_t)(gn0 + r0 + srow) * IN_N + kt + schunk * 8),
                  Bs + (size_t)r0 * BK);
    }
    __syncthreads();   // drains vmcnt (global_load_lds)

#pragma unroll
    for (int kk = 0; kk < 2; ++kk) {
      bf16x8 af[4], bfr[4];
      const int q = kk * 4 + qbase;            // logical 16B chunk 0..7
#pragma unroll
      for (int i = 0; i < 4; ++i) {
        af[i]  = *(const bf16x8*)&As[(fra + i * 16) * BK + (q ^ l7) * 8];
        bfr[i] = *(const bf16x8*)&Bs[(frb + i * 16) * BK + (q ^ l7) * 8];
      }
#pragma unroll
      for (int mi = 0; mi < 4; ++mi)
#pragma unroll
        for (int ni = 0; ni < 4; ++ni)
          acc[mi][ni] = __builtin_amdgcn_mfma_f32_16x16x32_bf16(af[mi], bfr[ni], acc[mi][ni], 0, 0, 0);
    }
    __syncthreads();
  }

  // epilogue: C/D layout col = lane&15, row = (lane>>4)*4 + r   [m89/m91]
  const int col0 = gn0 + wn * 64 + (lane & 15);
  const int row0 = gm0 + wm * 64 + (lane >> 4) * 4;
#pragma unroll
  for (int mi = 0; mi < 4; ++mi) {
#pragma unroll
    for (int ni = 0; ni < 4; ++ni) {
      int col = col0 + ni * 16;
      float bv = bias[col];
#pragma unroll
      for (int r = 0; r < 4; ++r) {
        int row = row0 + mi * 16 + r;
        C[(size_t)row * OUT_N + col] = acc[mi][ni][r] + bv;
      }
    }
  }
}

// ---------------------------------------------------------------------------
extern "C" void kernel_launch(void* const* d_in, const int* in_sizes, int n_in,
                              void* d_out, int out_size, void* d_ws, size_t ws_size,
                              hipStream_t stream) {
  const float* data = (const float*)d_in[0];
  const float* wr   = (const float*)d_in[1];
  const float* wi   = (const float*)d_in[2];
  const float* bias = (const float*)d_in[3];
  const int*   zmat = (const int*)d_in[4];

  char* ws = (char*)d_ws;
  float2* wt = (float2*)ws;                                  // 2049*4096*8
  float2* y  = (float2*)(ws + 67141632ull);                  // 4096*2049*8
  unsigned short* wbf = (unsigned short*)ws;                 // 4096*4096*2
  unsigned short* dbf = (unsigned short*)(ws + 33554432ull); // 2048*4096*2

  hipLaunchKernelGGL(mask_transpose, dim3(33, 128), dim3(32, 8), 0, stream, wr, wi, zmat, wt);
  hipLaunchKernelGGL(col_ifft,       dim3(2049),    dim3(256),   0, stream, wt);
  hipLaunchKernelGGL(transpose_ko,   dim3(65, 128), dim3(32, 8), 0, stream, wt, y);
  hipLaunchKernelGGL(row_irfft2,     dim3(2048),    dim3(256),   0, stream, y, wbf);
  hipLaunchKernelGGL(cvt_bf16,       dim3(8192),    dim3(256),   0, stream, data, dbf, (BATCH * IN_N) / 4);
  hipLaunchKernelGGL(gemm_bt_bias,   dim3(OUT_N / 128, BATCH / 128), dim3(256), 0, stream,
                     dbf, wbf, bias, (float*)d_out);
}